// Round 5
// baseline (359.017 us; speedup 1.0000x reference)
//
#include <hip/hip_runtime.h>

#define HID 4096
#define NTOK 4096

typedef float f32x4 __attribute__((ext_vector_type(4)));

// ---- helpers -------------------------------------------------------------

__device__ inline unsigned int pack_fp8x4(float a, float b, float c, float d) {
  // v_cvt_pk_fp8_f32 is RNE saturating on gfx950 (OCP e4m3fn)
  int p = __builtin_amdgcn_cvt_pk_fp8_f32(a, b, 0, false);   // bytes 0,1
  p = __builtin_amdgcn_cvt_pk_fp8_f32(c, d, p, true);        // bytes 2,3
  return (unsigned int)p;
}

__device__ inline void gload16(const void* g, void* l) {
  __builtin_amdgcn_global_load_lds(
      (const __attribute__((address_space(1))) unsigned int*)g,
      (__attribute__((address_space(3))) unsigned int*)l, 16, 0, 0);
}

// ---- fused prep: silu-quant (blocks 0..8191) + w transpose (blocks 8192+) -

#define NB_SILU 8192

__global__ __launch_bounds__(256) void k_prep(
    const float* __restrict__ x, const float* __restrict__ w,
    const float* __restrict__ wscale, unsigned char* __restrict__ q8,
    unsigned char* __restrict__ wT8) {
  const int t = threadIdx.x;
  if (blockIdx.x < NB_SILU) {
    // ---- y = silu(gate)*up ; q8 = fp8(clip(y/s)) ----
    const float s = wscale[0];
    const int idx = blockIdx.x * 256 + t;           // 8 elems each
    const int row = idx >> 9;                        // 512 threads per row
    const int col = (idx & 511) * 8;
    const float* gp = x + (size_t)row * (2 * HID) + col;
    f32x4 g0 = *(const f32x4*)gp;
    f32x4 g1 = *(const f32x4*)(gp + 4);
    f32x4 u0 = *(const f32x4*)(gp + HID);
    f32x4 u1 = *(const f32x4*)(gp + HID + 4);
    float q[8];
#pragma unroll
    for (int j = 0; j < 4; ++j) {
      float g = g0[j];
      float sg = 1.0f / (1.0f + expf(-g));
      float v = (g * sg * u0[j]) / s;
      q[j] = fminf(fmaxf(v, -448.0f), 448.0f);
    }
#pragma unroll
    for (int j = 0; j < 4; ++j) {
      float g = g1[j];
      float sg = 1.0f / (1.0f + expf(-g));
      float v = (g * sg * u1[j]) / s;
      q[4 + j] = fminf(fmaxf(v, -448.0f), 448.0f);
    }
    unsigned int lo = pack_fp8x4(q[0], q[1], q[2], q[3]);
    unsigned int hi = pack_fp8x4(q[4], q[5], q[6], q[7]);
    unsigned long long pk = ((unsigned long long)hi << 32) | lo;
    *(unsigned long long*)(q8 + (size_t)idx * 8) = pk;
  } else {
    // ---- wT8[n][k] = fp8(w[k][n]) (exact: w is fp8-representable) ----
    __shared__ float lds[64][65];   // +1 pad: conflict-free col reads
    const int bid = blockIdx.x - NB_SILU;
    const int bk = (bid >> 6) * 64;   // K-tile origin
    const int bn = (bid & 63) * 64;   // N-tile origin
#pragma unroll
    for (int it = 0; it < 4; ++it) {
      int f = t + it * 256;        // 0..1023 float4 slots
      int r = f >> 4;              // k row 0..63
      int c = (f & 15) * 4;        // n col
      f32x4 v = *(const f32x4*)(w + (size_t)(bk + r) * HID + bn + c);
      lds[r][c + 0] = v.x; lds[r][c + 1] = v.y;
      lds[r][c + 2] = v.z; lds[r][c + 3] = v.w;
    }
    __syncthreads();
    const int n = t >> 2;            // 0..63 output row (N dim)
    const int ch = (t & 3) * 16;     // k chunk of 16
    unsigned int pk[4];
#pragma unroll
    for (int qq = 0; qq < 4; ++qq) {
      float a = lds[ch + 4 * qq + 0][n];
      float b = lds[ch + 4 * qq + 1][n];
      float c2 = lds[ch + 4 * qq + 2][n];
      float d = lds[ch + 4 * qq + 3][n];
      pk[qq] = pack_fp8x4(a, b, c2, d);
    }
    uint4 vv; vv.x = pk[0]; vv.y = pk[1]; vv.z = pk[2]; vv.w = pk[3];
    *(uint4*)(wT8 + (size_t)(bn + n) * HID + bk + ch) = vv;
  }
}

// ---- GEMM: out[m][n] = s^2 * sum_k q8[m][k] * wT8[n][k] ------------------
// 128x128 tile, BK=128 fp8, 4 waves, 16x16x32 fp8 MFMA.
// LDS: 16B-chunk XOR swizzle chunk' = chunk ^ (row&7), both sides
// (pre-swizzled global_load_lds source + swizzled ds_read addr), linear dest.
// T3-minimum 2-phase pipeline: double-buffered LDS; next tile's 8
// global_load_lds issued BEFORE computing current tile; ONE __syncthreads
// per iter at the end (its vmcnt(0) lands after the compute phase covers
// the load latency).

#define BM 128
#define BN 128
#define BK 128
#define NT (HID / BK)

__global__ __launch_bounds__(256) void k_gemm_fp8(
    const unsigned char* __restrict__ A8, const unsigned char* __restrict__ B8,
    const float* __restrict__ wscale, float* __restrict__ out) {
  __shared__ unsigned char sA[2][BM * BK];   // 2 x 16 KB
  __shared__ unsigned char sB[2][BN * BK];   // 2 x 16 KB
  const int t = threadIdx.x;
  const int lane = t & 63;
  const int hi = lane >> 4;               // k-group within fragment
  const int wv = t >> 6;                  // wave 0..3
  const int wr = wv >> 1, wc = wv & 1;    // 2x2 waves of 64x64
  const int bid = blockIdx.x;
  const int brow = (bid >> 5) * BM;       // 32 row-blocks x 32 col-blocks
  const int bcol = (bid & 31) * BN;

  f32x4 acc[4][4] = {};

  // --- staging (pre-swizzled source), thread t covers LDS chunks t+256j ---
  // row(q)=q>>3=(t>>3)+32j ; dest chunk c'=t&7 ; src chunk c = c'^(row&7)
  const int csrc16 = (((t & 7) ^ ((t >> 3) & 7)) * 16);
  const int r0 = t >> 3;
  const unsigned char* gA = A8 + (size_t)(brow + r0) * HID + csrc16;
  const unsigned char* gB = B8 + (size_t)(bcol + r0) * HID + csrc16;
  const size_t rowstep = (size_t)32 * HID;   // j advances 32 rows

  // --- fragment read offsets (loop-invariant) ---
  // frag(row,ks): byte = row*128 + ((2ks+(hi>>1)) ^ (row&7))*16 + (hi&1)*8
  const int arow = 64 * wr + (lane & 15);
  const int brw = 64 * wc + (lane & 15);
  int ks_off[4];
#pragma unroll
  for (int ks = 0; ks < 4; ++ks)
    ks_off[ks] = (((2 * ks + (hi >> 1)) ^ (lane & 7)) * 16) + (hi & 1) * 8;

  // --- prologue: stage K-tile 0 into buffer 0 ---
#pragma unroll
  for (int j = 0; j < 4; ++j) {
    gload16(gA + j * rowstep, &sA[0][t * 16 + j * 4096]);
    gload16(gB + j * rowstep, &sB[0][t * 16 + j * 4096]);
  }
  __syncthreads();   // drain prologue staging

  int cur = 0;
  for (int it = 0; it < NT; ++it) {
    // issue next tile's staging into the other buffer (overlaps compute)
    if (it + 1 < NT) {
      const int kt = (it + 1) * BK;
#pragma unroll
      for (int j = 0; j < 4; ++j) {
        gload16(gA + kt + j * rowstep, &sA[cur ^ 1][t * 16 + j * 4096]);
        gload16(gB + kt + j * rowstep, &sB[cur ^ 1][t * 16 + j * 4096]);
      }
    }
    // compute current tile
    const unsigned char* __restrict__ pA = &sA[cur][0];
    const unsigned char* __restrict__ pB = &sB[cur][0];
#pragma unroll
    for (int ks = 0; ks < 4; ++ks) {
      long long af[4], bf[4];
#pragma unroll
      for (int i = 0; i < 4; ++i) {
        af[i] = *(const long long*)&pA[(arow + 16 * i) * BK + ks_off[ks]];
        bf[i] = *(const long long*)&pB[(brw + 16 * i) * BK + ks_off[ks]];
      }
#pragma unroll
      for (int i = 0; i < 4; ++i)
#pragma unroll
        for (int j = 0; j < 4; ++j)
          acc[i][j] = __builtin_amdgcn_mfma_f32_16x16x32_fp8_fp8(
              af[i], bf[j], acc[i][j], 0, 0, 0);
    }
    // one barrier per iter: drains vmcnt(0) (next tile staged) AFTER the
    // compute phase covered the latency; also orders buf reuse.
    __syncthreads();
    cur ^= 1;
  }

  const float s = wscale[0];
  const float s2 = s * s;
#pragma unroll
  for (int i = 0; i < 4; ++i) {
    int row0 = brow + 64 * wr + 16 * i + ((lane >> 4) * 4);
#pragma unroll
    for (int j = 0; j < 4; ++j) {
      int col = bcol + 64 * wc + 16 * j + (lane & 15);
#pragma unroll
      for (int r = 0; r < 4; ++r)
        out[(size_t)(row0 + r) * HID + col] = acc[i][j][r] * s2;
    }
  }
}

// ---- launch --------------------------------------------------------------

extern "C" void kernel_launch(void* const* d_in, const int* in_sizes, int n_in,
                              void* d_out, int out_size, void* d_ws, size_t ws_size,
                              hipStream_t stream) {
  const float* x = (const float*)d_in[0];        // [4096][8192]
  const float* w = (const float*)d_in[1];        // [4096][4096]
  const float* wscale = (const float*)d_in[2];   // [1]
  float* out = (float*)d_out;                    // [4096][4096]

  unsigned char* q8 = (unsigned char*)d_ws;                    // 16 MB
  unsigned char* wT8 = q8 + (size_t)NTOK * HID;                // 16 MB

  // fused silu-quant (8192 blocks) + w transpose-quant (4096 blocks)
  k_prep<<<NB_SILU + (HID / 64) * (HID / 64), 256, 0, stream>>>(x, w, wscale,
                                                                q8, wT8);
  // fp8 GEMM, 2-phase double-buffered
  k_gemm_fp8<<<(NTOK / BM) * (HID / BN), 256, 0, stream>>>(q8, wT8, wscale, out);
}

// Round 6
// 323.258 us; speedup vs baseline: 1.1106x; 1.1106x over previous
//
#include <hip/hip_runtime.h>

#define HID 4096
#define NTOK 4096

typedef float f32x4 __attribute__((ext_vector_type(4)));
typedef int i32x4 __attribute__((ext_vector_type(4)));
typedef int i32x8 __attribute__((ext_vector_type(8)));

// ---- helpers -------------------------------------------------------------

__device__ inline unsigned int pack_fp8x4(float a, float b, float c, float d) {
  // v_cvt_pk_fp8_f32 is RNE saturating on gfx950 (OCP e4m3fn)
  int p = __builtin_amdgcn_cvt_pk_fp8_f32(a, b, 0, false);   // bytes 0,1
  p = __builtin_amdgcn_cvt_pk_fp8_f32(c, d, p, true);        // bytes 2,3
  return (unsigned int)p;
}

__device__ inline void gload16(const void* g, void* l) {
  __builtin_amdgcn_global_load_lds(
      (const __attribute__((address_space(1))) unsigned int*)g,
      (__attribute__((address_space(3))) unsigned int*)l, 16, 0, 0);
}

// ---- fused prep: silu-quant (blocks 0..8191) + w transpose (blocks 8192+) -

#define NB_SILU 8192

__global__ __launch_bounds__(256) void k_prep(
    const float* __restrict__ x, const float* __restrict__ w,
    const float* __restrict__ wscale, unsigned char* __restrict__ q8,
    unsigned char* __restrict__ wT8) {
  const int t = threadIdx.x;
  if (blockIdx.x < NB_SILU) {
    // ---- y = silu(gate)*up ; q8 = fp8(clip(y/s)) ----
    const float s = wscale[0];
    const int idx = blockIdx.x * 256 + t;           // 8 elems each
    const int row = idx >> 9;                        // 512 threads per row
    const int col = (idx & 511) * 8;
    const float* gp = x + (size_t)row * (2 * HID) + col;
    f32x4 g0 = *(const f32x4*)gp;
    f32x4 g1 = *(const f32x4*)(gp + 4);
    f32x4 u0 = *(const f32x4*)(gp + HID);
    f32x4 u1 = *(const f32x4*)(gp + HID + 4);
    float q[8];
#pragma unroll
    for (int j = 0; j < 4; ++j) {
      float g = g0[j];
      float sg = 1.0f / (1.0f + expf(-g));
      float v = (g * sg * u0[j]) / s;
      q[j] = fminf(fmaxf(v, -448.0f), 448.0f);
    }
#pragma unroll
    for (int j = 0; j < 4; ++j) {
      float g = g1[j];
      float sg = 1.0f / (1.0f + expf(-g));
      float v = (g * sg * u1[j]) / s;
      q[4 + j] = fminf(fmaxf(v, -448.0f), 448.0f);
    }
    unsigned int lo = pack_fp8x4(q[0], q[1], q[2], q[3]);
    unsigned int hi = pack_fp8x4(q[4], q[5], q[6], q[7]);
    unsigned long long pk = ((unsigned long long)hi << 32) | lo;
    *(unsigned long long*)(q8 + (size_t)idx * 8) = pk;
  } else {
    // ---- wT8[n][k] = fp8(w[k][n]) (exact: w is fp8-representable) ----
    __shared__ float lds[64][65];   // +1 pad: conflict-free col reads
    const int bid = blockIdx.x - NB_SILU;
    const int bk = (bid >> 6) * 64;   // K-tile origin
    const int bn = (bid & 63) * 64;   // N-tile origin
#pragma unroll
    for (int it = 0; it < 4; ++it) {
      int f = t + it * 256;        // 0..1023 float4 slots
      int r = f >> 4;              // k row 0..63
      int c = (f & 15) * 4;        // n col
      f32x4 v = *(const f32x4*)(w + (size_t)(bk + r) * HID + bn + c);
      lds[r][c + 0] = v.x; lds[r][c + 1] = v.y;
      lds[r][c + 2] = v.z; lds[r][c + 3] = v.w;
    }
    __syncthreads();
    const int n = t >> 2;            // 0..63 output row (N dim)
    const int ch = (t & 3) * 16;     // k chunk of 16
    unsigned int pk[4];
#pragma unroll
    for (int qq = 0; qq < 4; ++qq) {
      float a = lds[ch + 4 * qq + 0][n];
      float b = lds[ch + 4 * qq + 1][n];
      float c2 = lds[ch + 4 * qq + 2][n];
      float d = lds[ch + 4 * qq + 3][n];
      pk[qq] = pack_fp8x4(a, b, c2, d);
    }
    uint4 vv; vv.x = pk[0]; vv.y = pk[1]; vv.z = pk[2]; vv.w = pk[3];
    *(uint4*)(wT8 + (size_t)(bn + n) * HID + bk + ch) = vv;
  }
}

// ---- GEMM: out[m][n] = s^2 * sum_k q8[m][k] * wT8[n][k] ------------------
// 128x128 tile, BK=128 fp8, 4 waves, MX-scaled mfma_scale_16x16x128_f8f6f4
// with unit scales (E8M0 0x7F = 2^0): exact fp8 matmul at 2x non-scaled rate
// (m148 precedent: 995 -> 1628 TF on this same structure).
// LDS: 16B-chunk XOR swizzle chunk' = chunk ^ (row&7), both sides
// (pre-swizzled global_load_lds source + swizzled ds_read addr), linear dest.
// Double-buffered, one __syncthreads per K-iter.

#define BM 128
#define BN 128
#define BK 128
#define NT (HID / BK)

__global__ __launch_bounds__(256) void k_gemm_fp8(
    const unsigned char* __restrict__ A8, const unsigned char* __restrict__ B8,
    const float* __restrict__ wscale, float* __restrict__ out) {
  __shared__ unsigned char sA[2][BM * BK];   // 2 x 16 KB
  __shared__ unsigned char sB[2][BN * BK];   // 2 x 16 KB
  const int t = threadIdx.x;
  const int lane = t & 63;
  const int wv = t >> 6;                  // wave 0..3
  const int wr = wv >> 1, wc = wv & 1;    // 2x2 waves of 64x64
  const int bid = blockIdx.x;
  const int brow = (bid >> 5) * BM;       // 32 row-blocks x 32 col-blocks
  const int bcol = (bid & 31) * BN;

  f32x4 acc[4][4] = {};

  // --- staging (pre-swizzled source), thread t covers LDS chunks t+256j ---
  // row(q)=q>>3=(t>>3)+32j ; dest chunk c'=t&7 ; src chunk c = c'^(row&7)
  const int csrc16 = (((t & 7) ^ ((t >> 3) & 7)) * 16);
  const int r0 = t >> 3;
  const unsigned char* gA = A8 + (size_t)(brow + r0) * HID + csrc16;
  const unsigned char* gB = B8 + (size_t)(bcol + r0) * HID + csrc16;
  const size_t rowstep = (size_t)32 * HID;   // j advances 32 rows

  // --- fragment read offsets (loop-invariant) ---
  // 16x16x128 A/B frag: lane holds row (lane&15), 32 k-bytes at k-group
  // hi=lane>>4: bytes [hi*32, hi*32+32) -> swizzled chunks (2hi)^(row&7),
  // (2hi+1)^(row&7). row&7 == lane&7 for all frag rows (16i + 64w ≡ 0 mod 8).
  const int arow = 64 * wr + (lane & 15);
  const int brw = 64 * wc + (lane & 15);
  const int sxor = lane & 7;
  const int c0 = (((lane >> 4) * 2) ^ sxor) * 16;
  const int c1 = (((lane >> 4) * 2 + 1) ^ sxor) * 16;

  // --- prologue: stage K-tile 0 into buffer 0 ---
#pragma unroll
  for (int j = 0; j < 4; ++j) {
    gload16(gA + j * rowstep, &sA[0][t * 16 + j * 4096]);
    gload16(gB + j * rowstep, &sB[0][t * 16 + j * 4096]);
  }
  __syncthreads();   // drain prologue staging

  int cur = 0;
  for (int it = 0; it < NT; ++it) {
    // issue next tile's staging into the other buffer (overlaps compute)
    if (it + 1 < NT) {
      const int kt = (it + 1) * BK;
#pragma unroll
      for (int j = 0; j < 4; ++j) {
        gload16(gA + kt + j * rowstep, &sA[cur ^ 1][t * 16 + j * 4096]);
        gload16(gB + kt + j * rowstep, &sB[cur ^ 1][t * 16 + j * 4096]);
      }
    }
    // compute current tile: one 16x16x128 MFMA per (i,j)
    const unsigned char* __restrict__ pA = &sA[cur][0];
    const unsigned char* __restrict__ pB = &sB[cur][0];
    i32x8 af[4], bf[4];
#pragma unroll
    for (int i = 0; i < 4; ++i) {
      const unsigned char* ra = &pA[(arow + 16 * i) * BK];
      i32x4 lo = *(const i32x4*)(ra + c0);
      i32x4 hi4 = *(const i32x4*)(ra + c1);
      af[i] = __builtin_shufflevector(lo, hi4, 0, 1, 2, 3, 4, 5, 6, 7);
      const unsigned char* rb = &pB[(brw + 16 * i) * BK];
      i32x4 lob = *(const i32x4*)(rb + c0);
      i32x4 hib = *(const i32x4*)(rb + c1);
      bf[i] = __builtin_shufflevector(lob, hib, 0, 1, 2, 3, 4, 5, 6, 7);
    }
#pragma unroll
    for (int i = 0; i < 4; ++i)
#pragma unroll
      for (int j = 0; j < 4; ++j)
        acc[i][j] = __builtin_amdgcn_mfma_scale_f32_16x16x128_f8f6f4(
            af[i], bf[j], acc[i][j], 0 /*cbsz: fp8*/, 0 /*blgp: fp8*/,
            0, 0x7F7F7F7F /*scale_a = 1.0*/, 0, 0x7F7F7F7F /*scale_b = 1.0*/);
    // one barrier per iter: drains vmcnt(0) (next tile staged) AFTER the
    // compute phase covered the latency; also orders buf reuse.
    __syncthreads();
    cur ^= 1;
  }

  const float s = wscale[0];
  const float s2 = s * s;
#pragma unroll
  for (int i = 0; i < 4; ++i) {
    int row0 = brow + 64 * wr + 16 * i + ((lane >> 4) * 4);
#pragma unroll
    for (int j = 0; j < 4; ++j) {
      int col = bcol + 64 * wc + 16 * j + (lane & 15);
#pragma unroll
      for (int r = 0; r < 4; ++r)
        out[(size_t)(row0 + r) * HID + col] = acc[i][j][r] * s2;
    }
  }
}

// ---- launch --------------------------------------------------------------

extern "C" void kernel_launch(void* const* d_in, const int* in_sizes, int n_in,
                              void* d_out, int out_size, void* d_ws, size_t ws_size,
                              hipStream_t stream) {
  const float* x = (const float*)d_in[0];        // [4096][8192]
  const float* w = (const float*)d_in[1];        // [4096][4096]
  const float* wscale = (const float*)d_in[2];   // [1]
  float* out = (float*)d_out;                    // [4096][4096]

  unsigned char* q8 = (unsigned char*)d_ws;                    // 16 MB
  unsigned char* wT8 = q8 + (size_t)NTOK * HID;                // 16 MB

  // fused silu-quant (8192 blocks) + w transpose-quant (4096 blocks)
  k_prep<<<NB_SILU + (HID / 64) * (HID / 64), 256, 0, stream>>>(x, w, wscale,
                                                                q8, wT8);
  // MX-scaled fp8 GEMM (unit scales), 2-phase double-buffered
  k_gemm_fp8<<<(NTOK / BM) * (HID / BN), 256, 0, stream>>>(q8, wT8, wscale, out);
}